// Round 2
// baseline (3197.370 us; speedup 1.0000x reference)
//
#include <hip/hip_runtime.h>
#include <cstddef>

#define TT 256
#define HH 128
#define ENC_STRIDE 132

// LDS: prologue staging buffer (enc_proj) overlaps the steady-state arrays.
struct __align__(16) Steady {
  float w2t[HH * 132];   // W2 transposed: w2t[k*132 + j] = W2[j][k]  (67584 B)
  float uvl[2 * HH];     // interleaved: uvl[2k]=uc2*C2 (per step), uvl[2k+1]=-2*V[k]
  float h[HH];
  float xloc[TT * 2];
  float red_s[8];
  int   red_t[8];
  float red_sum[8];
  float sv;              // sum(V)
};
union __align__(16) SM {
  float enc_stage[TT * ENC_STRIDE];   // 135168 B, prologue only
  Steady s;                            // ~71.5 KB, steady state
};

__device__ __forceinline__ float fast_sigmoid(float x) {
  const float L2E = 1.4426950408889634f;
  float y = __builtin_amdgcn_exp2f(-x * L2E);
  return __builtin_amdgcn_rcpf(1.0f + y);
}
__device__ __forceinline__ float fast_tanh(float x) {
  const float C2 = 2.8853900817779268f;   // 2*log2(e)
  float y = __builtin_amdgcn_exp2f(x * C2);
  return 1.0f - 2.0f * __builtin_amdgcn_rcpf(1.0f + y);
}

// One workgroup per batch element; 512 threads = 8 waves; 256 steps in-kernel.
// enc_proj lives in REGISTERS (64/thread); Wr column in registers (128/thread).
__global__ __launch_bounds__(512, 2)
void decoder_kernel(const float* __restrict__ x,
                    const float* __restrict__ enc_output,
                    const float* __restrict__ h0,
                    const float* __restrict__ c0,
                    const float* __restrict__ W1,
                    const float* __restrict__ W2,
                    const float* __restrict__ V,
                    const float* __restrict__ Wk,
                    const float* __restrict__ Wr,
                    const float* __restrict__ bias,
                    float* __restrict__ out)
{
  __shared__ SM sm;
  const int u = threadIdx.x;
  const int b = blockIdx.x;
  const float C2  = 2.8853900817779268f;   // 2*log2(e)
  const float L2E = 1.4426950408889634f;

  // ---------------- P0: enc_proj = enc_output[b] @ W1 -> LDS staging ----------------
  {
    const float* encb = enc_output + (size_t)b * TT * HH;
    const int tsub = u >> 4;
    const int ks   = (u & 15) * 8;
    for (int p = 0; p < 8; ++p) {
      const int t = p * 32 + tsub;
      float4 a0 = {0.f, 0.f, 0.f, 0.f};
      float4 a1 = {0.f, 0.f, 0.f, 0.f};
      const float4* er4 = (const float4*)(encb + t * HH);
      for (int j4 = 0; j4 < 32; ++j4) {
        const float4 ev = er4[j4];
        const float* w1p = W1 + (j4 * 4) * HH + ks;
        float4 wa, wb;
        wa = *(const float4*)(w1p + 0 * HH); wb = *(const float4*)(w1p + 0 * HH + 4);
        a0.x += ev.x * wa.x; a0.y += ev.x * wa.y; a0.z += ev.x * wa.z; a0.w += ev.x * wa.w;
        a1.x += ev.x * wb.x; a1.y += ev.x * wb.y; a1.z += ev.x * wb.z; a1.w += ev.x * wb.w;
        wa = *(const float4*)(w1p + 1 * HH); wb = *(const float4*)(w1p + 1 * HH + 4);
        a0.x += ev.y * wa.x; a0.y += ev.y * wa.y; a0.z += ev.y * wa.z; a0.w += ev.y * wa.w;
        a1.x += ev.y * wb.x; a1.y += ev.y * wb.y; a1.z += ev.y * wb.z; a1.w += ev.y * wb.w;
        wa = *(const float4*)(w1p + 2 * HH); wb = *(const float4*)(w1p + 2 * HH + 4);
        a0.x += ev.z * wa.x; a0.y += ev.z * wa.y; a0.z += ev.z * wa.z; a0.w += ev.z * wa.w;
        a1.x += ev.z * wb.x; a1.y += ev.z * wb.y; a1.z += ev.z * wb.z; a1.w += ev.z * wb.w;
        wa = *(const float4*)(w1p + 3 * HH); wb = *(const float4*)(w1p + 3 * HH + 4);
        a0.x += ev.w * wa.x; a0.y += ev.w * wa.y; a0.z += ev.w * wa.z; a0.w += ev.w * wa.w;
        a1.x += ev.w * wb.x; a1.y += ev.w * wb.y; a1.z += ev.w * wb.z; a1.w += ev.w * wb.w;
      }
      *(float4*)(&sm.enc_stage[t * ENC_STRIDE + ks])     = a0;
      *(float4*)(&sm.enc_stage[t * ENC_STRIDE + ks + 4]) = a1;
    }
  }
  __syncthreads();   // staging complete

  // ---------------- P1: pull enc row-half into registers (prescaled by C2) ----------
  const int t    = u >> 1;       // phase-D row
  const int half = u & 1;        // phase-D k-half
  float encreg[64];
  {
    const float* er = &sm.enc_stage[t * ENC_STRIDE + 64 * half];
    #pragma unroll
    for (int i = 0; i < 64; i += 4) {
      float4 ev = *(const float4*)(er + i);
      encreg[i + 0] = ev.x * C2;
      encreg[i + 1] = ev.y * C2;
      encreg[i + 2] = ev.z * C2;
      encreg[i + 3] = ev.w * C2;
    }
  }

  // Persistent per-thread LSTM weights: gate g=u&3, unit m=u>>2, col=g*128+m.
  const int g = u & 3;
  const int m = u >> 2;
  const int col = g * HH + m;
  const float wk0 = Wk[col];
  const float wk1 = Wk[512 + col];
  const float bb  = bias[col];
  float wrreg[HH];
  #pragma unroll
  for (int k = 0; k < HH; ++k) wrreg[k] = Wr[k * 512 + col];
  float c = c0[b * HH + m];
  float ptr0 = 1.0f, ptr1 = 1.0f;

  __syncthreads();   // all staging reads complete; safe to overwrite union

  // ---------------- P2: init steady-state LDS ----------------
  {
    // W2 transpose: w2t[k*132 + j] = W2[j][k]
    const int jj = u & 127;
    const int kc = u >> 7;     // 0..3
    #pragma unroll
    for (int kq = 0; kq < 8; ++kq) {
      float4 wv = *(const float4*)(W2 + jj * HH + kc * 32 + kq * 4);
      const int k0 = kc * 32 + kq * 4;
      sm.s.w2t[(k0 + 0) * 132 + jj] = wv.x;
      sm.s.w2t[(k0 + 1) * 132 + jj] = wv.y;
      sm.s.w2t[(k0 + 2) * 132 + jj] = wv.z;
      sm.s.w2t[(k0 + 3) * 132 + jj] = wv.w;
    }
    sm.s.xloc[u] = x[b * (TT * 2) + u];
    if (u < HH) {
      sm.s.h[u] = h0[b * HH + u];
      sm.s.uvl[2 * u + 1] = -2.0f * V[u];
    }
    if (u < 64) {
      float v = V[u] + V[u + 64];
      #pragma unroll
      for (int o = 1; o < 64; o <<= 1) v += __shfl_xor(v, o, 64);
      if (u == 0) sm.s.sv = v;
    }
  }
  __syncthreads();
  const float svr = sm.s.sv;
  float* outb = out + (size_t)b * TT * TT;

  // ---------------- step loop ----------------
  #pragma unroll 1
  for (int step = 0; step < TT; ++step) {
    // ---- A: z[col] = b + ptr@Wk + h@Wr (Wr in regs, h broadcast b128 from LDS) ----
    float z0 = bb + ptr0 * wk0;
    float z1 = ptr1 * wk1, z2 = 0.0f, z3 = 0.0f;
    const float4* h4 = (const float4*)sm.s.h;
    #pragma unroll
    for (int k4 = 0; k4 < 32; ++k4) {
      float4 hv = h4[k4];
      z0 += hv.x * wrreg[4 * k4 + 0];
      z1 += hv.y * wrreg[4 * k4 + 1];
      z2 += hv.z * wrreg[4 * k4 + 2];
      z3 += hv.w * wrreg[4 * k4 + 3];
    }
    float z = (z0 + z1) + (z2 + z3);
    // quad exchange: all 4 gate preactivations to every lane of the quad
    float za = __shfl_xor(z, 1);
    float zb = __shfl_xor(z, 2);
    float zc = __shfl_xor(za, 2);
    float zi = (g == 0) ? z  : (g == 1) ? za : (g == 2) ? zb : zc;
    float zf = (g == 0) ? za : (g == 1) ? z  : (g == 2) ? zc : zb;
    float zg = (g == 0) ? zb : (g == 1) ? zc : (g == 2) ? z  : za;
    float zo = (g == 0) ? zc : (g == 1) ? zb : (g == 2) ? za : z;
    float ig = fast_sigmoid(zi);
    float fg = fast_sigmoid(zf);
    float gg = fast_tanh(zg);
    float og = fast_sigmoid(zo);
    c = fg * c + ig * gg;
    float hn = og * fast_tanh(c);

    __syncthreads();                 // (alpha) all reads of old h complete
    if (g == 0) sm.s.h[m] = hn;
    __syncthreads();                 // (beta) new h visible

    // ---- C: uvl[2k] = (h @ W2)[k] * C2. Thread: k=u>>2, j ≡ jq (mod 4), jq=u&3 ----
    {
      const int k  = u >> 2;
      const int jq = u & 3;
      float p0 = 0.0f, p1 = 0.0f;
      #pragma unroll
      for (int jj = 0; jj < 32; jj += 2) {
        const int ja = 4 * jj + jq;
        const int jb = 4 * (jj + 1) + jq;
        p0 += sm.s.h[ja] * sm.s.w2t[k * 132 + ja];
        p1 += sm.s.h[jb] * sm.s.w2t[k * 132 + jb];
      }
      float part = p0 + p1;
      part += __shfl_xor(part, 1);
      part += __shfl_xor(part, 2);
      if (jq == 0) sm.s.uvl[2 * k] = part * C2;
    }
    __syncthreads();                 // (gamma) uc2 visible

    // ---- D: score[t] = sv + sum_k (-2 V_k) * rcp(1 + exp2(C2*enc + C2*u)) ----
    const float4* uv4 = (const float4*)(sm.s.uvl + 128 * half);
    float a0 = 0.0f, a1 = 0.0f, a2 = 0.0f, a3 = 0.0f;
    #pragma unroll
    for (int c4 = 0; c4 < 32; c4 += 2) {
      float4 qa = uv4[c4];
      float4 qb = uv4[c4 + 1];
      a0 += qa.y * __builtin_amdgcn_rcpf(1.0f + __builtin_amdgcn_exp2f(encreg[2 * c4 + 0] + qa.x));
      a1 += qa.w * __builtin_amdgcn_rcpf(1.0f + __builtin_amdgcn_exp2f(encreg[2 * c4 + 1] + qa.z));
      a2 += qb.y * __builtin_amdgcn_rcpf(1.0f + __builtin_amdgcn_exp2f(encreg[2 * c4 + 2] + qb.x));
      a3 += qb.w * __builtin_amdgcn_rcpf(1.0f + __builtin_amdgcn_exp2f(encreg[2 * c4 + 3] + qb.z));
    }
    float tot = (a0 + a1) + (a2 + a3);
    tot += __shfl_xor(tot, 1);       // combine the two k-halves
    float score = svr + tot;

    // ---- argmax over t (first-max tie-break) ----
    float bs = score; int bt = t;
    #pragma unroll
    for (int o = 1; o < 64; o <<= 1) {
      float s2 = __shfl_xor(bs, o);
      int   t2 = __shfl_xor(bt, o);
      if (s2 > bs || (s2 == bs && t2 < bt)) { bs = s2; bt = t2; }
    }
    if ((u & 63) == 0) { sm.s.red_s[u >> 6] = bs; sm.s.red_t[u >> 6] = bt; }
    __syncthreads();                 // (delta) wave partials visible
    float fbs = sm.s.red_s[0]; int fbt = sm.s.red_t[0];
    #pragma unroll
    for (int w = 1; w < 8; ++w) {
      float s2 = sm.s.red_s[w]; int t2 = sm.s.red_t[w];
      if (s2 > fbs || (s2 == fbs && t2 < fbt)) { fbs = s2; fbt = t2; }
    }
    ptr0 = sm.s.xloc[fbt * 2 + 0];
    ptr1 = sm.s.xloc[fbt * 2 + 1];

    // ---- fused softmax: p = exp2((s - max)*log2e); block sum; write p/sum ----
    float p = __builtin_amdgcn_exp2f((score - fbs) * L2E);
    float ws = p;
    #pragma unroll
    for (int o = 1; o < 64; o <<= 1) ws += __shfl_xor(ws, o);   // counts each t twice
    if ((u & 63) == 0) sm.s.red_sum[u >> 6] = ws;
    __syncthreads();                 // (epsilon) sum partials visible
    float sumtot = 0.0f;
    #pragma unroll
    for (int w = 0; w < 8; ++w) sumtot += sm.s.red_sum[w];
    sumtot *= 0.5f;
    if (half == 0) outb[(size_t)step * TT + t] = p * __builtin_amdgcn_rcpf(sumtot);
  }
}

extern "C" void kernel_launch(void* const* d_in, const int* in_sizes, int n_in,
                              void* d_out, int out_size, void* d_ws, size_t ws_size,
                              hipStream_t stream) {
  (void)in_sizes; (void)n_in; (void)d_ws; (void)ws_size; (void)out_size;
  const float* x    = (const float*)d_in[0];
  const float* enc  = (const float*)d_in[1];
  const float* h0   = (const float*)d_in[2];
  const float* c0   = (const float*)d_in[3];
  const float* W1   = (const float*)d_in[4];
  const float* W2   = (const float*)d_in[5];
  const float* V    = (const float*)d_in[6];
  const float* Wk   = (const float*)d_in[7];
  const float* Wr   = (const float*)d_in[8];
  const float* bias = (const float*)d_in[9];
  float* out = (float*)d_out;

  decoder_kernel<<<64, 512, 0, stream>>>(x, enc, h0, c0, W1, W2, V, Wk, Wr, bias, out);
}

// Round 4
// 1247.069 us; speedup vs baseline: 2.5639x; 2.5639x over previous
//
#include <hip/hip_runtime.h>
#include <cstddef>

#define TT 256
#define HH 128
#define EST 132   // E row stride in floats: lane t starts at bank 4t mod 32 ->
                  // every bank gets exactly 8 dwords per wave b128 = balanced

struct __align__(16) SMem {
  float E[TT * EST];      // 135168 B: exp2(C2 * enc_proj[t][k]) (staging for enc_proj first)
  float xloc[TT * 2];     // 2048 B
  float hbuf[HH];         // 512 B
  float part[8][64];      // 2048 B : phase-C partials (u_k)
  float scp[8][64];       // 2048 B : phase-D score partials
  float amax_s[4];
  int   amax_t[4];
  float ssum[4];
};                        // ~141.9 KB < 160 KB

__device__ __forceinline__ float rdlane(float v, int l) {
  return __int_as_float(__builtin_amdgcn_readlane(__float_as_int(v), l));
}
__device__ __forceinline__ float fast_sigmoid(float x) {
  const float L2E = 1.4426950408889634f;
  float y = __builtin_amdgcn_exp2f(-x * L2E);
  return __builtin_amdgcn_rcpf(1.0f + y);
}
__device__ __forceinline__ float fast_tanh(float x) {
  const float C2 = 2.8853900817779268f;   // 2*log2(e)
  float y = __builtin_amdgcn_exp2f(x * C2);
  return 1.0f - 2.0f * __builtin_amdgcn_rcpf(1.0f + y);
}

// One workgroup per batch element; 512 threads = 8 waves; 256 steps in-kernel.
// Wr column + W2 slice in registers; h in 2 VGPRs/lane (readlane broadcast);
// E=exp2(C2*enc_proj) in LDS; 1 transcendental pair (rcp) per score term.
__global__ __launch_bounds__(512, 2)
void decoder_kernel(const float* __restrict__ x,
                    const float* __restrict__ enc_output,
                    const float* __restrict__ h0,
                    const float* __restrict__ c0,
                    const float* __restrict__ W1,
                    const float* __restrict__ W2,
                    const float* __restrict__ V,
                    const float* __restrict__ Wk,
                    const float* __restrict__ Wr,
                    const float* __restrict__ bias,
                    float* __restrict__ out)
{
  __shared__ SMem sm;
  const int u    = threadIdx.x;
  const int b    = blockIdx.x;
  const int lane = u & 63;
  const int w    = u >> 6;      // wave 0..7
  const int half = w & 1;       // k-half for phases C/D
  const int tq   = w >> 1;      // 0..3
  const int t    = tq * 64 + lane;   // phase-D score row
  const float C2  = 2.8853900817779268f;
  const float L2E = 1.4426950408889634f;

  // ---------------- P0: enc_proj = enc_output[b] @ W1 -> sm.E (raw) ----------------
  {
    const float* encb = enc_output + (size_t)b * TT * HH;
    const int tsub = u >> 4;
    const int ks   = (u & 15) * 8;
    for (int p = 0; p < 8; ++p) {
      const int tt = p * 32 + tsub;
      float4 a0 = {0.f, 0.f, 0.f, 0.f};
      float4 a1 = {0.f, 0.f, 0.f, 0.f};
      const float4* er4 = (const float4*)(encb + tt * HH);
      for (int j4 = 0; j4 < 32; ++j4) {
        const float4 ev = er4[j4];
        const float* w1p = W1 + (j4 * 4) * HH + ks;
        float4 wa, wb;
        wa = *(const float4*)(w1p + 0 * HH); wb = *(const float4*)(w1p + 0 * HH + 4);
        a0.x += ev.x * wa.x; a0.y += ev.x * wa.y; a0.z += ev.x * wa.z; a0.w += ev.x * wa.w;
        a1.x += ev.x * wb.x; a1.y += ev.x * wb.y; a1.z += ev.x * wb.z; a1.w += ev.x * wb.w;
        wa = *(const float4*)(w1p + 1 * HH); wb = *(const float4*)(w1p + 1 * HH + 4);
        a0.x += ev.y * wa.x; a0.y += ev.y * wa.y; a0.z += ev.y * wa.z; a0.w += ev.y * wa.w;
        a1.x += ev.y * wb.x; a1.y += ev.y * wb.y; a1.z += ev.y * wb.z; a1.w += ev.y * wb.w;
        wa = *(const float4*)(w1p + 2 * HH); wb = *(const float4*)(w1p + 2 * HH + 4);
        a0.x += ev.z * wa.x; a0.y += ev.z * wa.y; a0.z += ev.z * wa.z; a0.w += ev.z * wa.w;
        a1.x += ev.z * wb.x; a1.y += ev.z * wb.y; a1.z += ev.z * wb.z; a1.w += ev.z * wb.w;
        wa = *(const float4*)(w1p + 3 * HH); wb = *(const float4*)(w1p + 3 * HH + 4);
        a0.x += ev.w * wa.x; a0.y += ev.w * wa.y; a0.z += ev.w * wa.z; a0.w += ev.w * wa.w;
        a1.x += ev.w * wb.x; a1.y += ev.w * wb.y; a1.z += ev.w * wb.z; a1.w += ev.w * wb.w;
      }
      *(float4*)(&sm.E[tt * EST + ks])     = a0;
      *(float4*)(&sm.E[tt * EST + ks + 4]) = a1;
    }
  }
  // small LDS inits (disjoint from E region)
  sm.xloc[u] = x[b * (TT * 2) + u];
  if (u < HH) sm.hbuf[u] = h0[b * HH + u];

  // ---------------- persistent registers ----------------
  const int g = u & 3;          // LSTM gate
  const int m = u >> 2;         // LSTM unit
  const int col = g * HH + m;
  const float wk0 = Wk[col];
  const float wk1 = Wk[512 + col];
  const float bb  = bias[col];
  float wrreg[HH];
  #pragma unroll
  for (int k = 0; k < HH; ++k) wrreg[k] = Wr[k * 512 + col];
  float w2col[32];              // W2[32*tq + jj][64*half + lane]
  #pragma unroll
  for (int jj = 0; jj < 32; ++jj) w2col[jj] = W2[(32 * tq + jj) * HH + 64 * half + lane];
  const float v2r = -2.0f * V[64 * half + lane];
  float c = c0[b * HH + m];
  float ptr0 = 1.0f, ptr1 = 1.0f;
  float svr;
  {
    float v = V[lane] + V[64 + lane];
    #pragma unroll
    for (int o = 1; o < 64; o <<= 1) v += __shfl_xor(v, o, 64);
    svr = v;
  }

  __syncthreads();   // P0 + small inits visible

  // ---------------- P1: E = exp2(C2 * enc_proj) in place (own phase-D data) -------
  {
    float* Er = &sm.E[t * EST + 64 * half];
    #pragma unroll
    for (int i = 0; i < 16; ++i) {
      float4 ev = *(const float4*)(Er + 4 * i);
      ev.x = __builtin_amdgcn_exp2f(ev.x * C2);
      ev.y = __builtin_amdgcn_exp2f(ev.y * C2);
      ev.z = __builtin_amdgcn_exp2f(ev.z * C2);
      ev.w = __builtin_amdgcn_exp2f(ev.w * C2);
      *(float4*)(Er + 4 * i) = ev;
    }
  }
  float hv0 = sm.hbuf[lane];
  float hv1 = sm.hbuf[64 + lane];
  __syncthreads();   // (zeta) RACE FIX: initial-h reads must complete before any
                     // wave's step-0 hbuf write. P1's LDS serialization skews
                     // waves by ~2000 cyc while phase A is VALU-only (~600 cyc),
                     // so without this barrier a fast wave overwrites hbuf while
                     // a slow wave is still reading h0 (round-3 failure).

  float* outb = out + (size_t)b * TT * TT;
  const float hsrc_sel = (tq < 2) ? 1.0f : 0.0f;  // phase C h source selector
  const int   jb = (tq & 1) * 32;

  // ---------------- step loop ----------------
  #pragma unroll 1
  for (int step = 0; step < TT; ++step) {
    // ---- A: z[col] = b + ptr@Wk + h@Wr  (readlane broadcast, regs only) ----
    float z0 = bb + ptr0 * wk0;
    float z1 = ptr1 * wk1;
    #pragma unroll
    for (int k = 0; k < 64; ++k) {
      z0 += rdlane(hv0, k) * wrreg[k];
      z1 += rdlane(hv1, k) * wrreg[64 + k];
    }
    float z = z0 + z1;
    // quad exchange: all 4 gate preactivations to every lane of the quad
    float za = __shfl_xor(z, 1);
    float zb = __shfl_xor(z, 2);
    float zc = __shfl_xor(za, 2);
    float zi = (g == 0) ? z  : (g == 1) ? za : (g == 2) ? zb : zc;
    float zf = (g == 0) ? za : (g == 1) ? z  : (g == 2) ? zc : zb;
    float zg = (g == 0) ? zb : (g == 1) ? zc : (g == 2) ? z  : za;
    float zo = (g == 0) ? zc : (g == 1) ? zb : (g == 2) ? za : z;
    float ig = fast_sigmoid(zi);
    float fg = fast_sigmoid(zf);
    float gg = fast_tanh(zg);
    float og = fast_sigmoid(zo);
    c = fg * c + ig * gg;
    float hn = og * fast_tanh(c);

    if (g == 0) sm.hbuf[m] = hn;   // old h lives in hv regs (in-loop reads are
                                   // behind beta/gamma/delta/eps barriers)
    __syncthreads();               // (beta) new h visible
    hv0 = sm.hbuf[lane];
    hv1 = sm.hbuf[64 + lane];

    // ---- C: u_k partial. wave w: j in [32*tq,+32), k = 64*half+lane ----
    {
      float hsrc = (hsrc_sel != 0.0f) ? hv0 : hv1;
      float cp0 = 0.0f, cp1 = 0.0f;
      #pragma unroll
      for (int jj = 0; jj < 32; jj += 2) {
        cp0 += rdlane(hsrc, jb + jj)     * w2col[jj];
        cp1 += rdlane(hsrc, jb + jj + 1) * w2col[jj + 1];
      }
      sm.part[w][lane] = cp0 + cp1;
    }
    __syncthreads();               // (gamma) partials visible

    // ---- U_k = exp2(C2 * u_k), per-lane for this half ----
    float us = (sm.part[half][lane]     + sm.part[half + 2][lane]) +
               (sm.part[half + 4][lane] + sm.part[half + 6][lane]);
    float Ur = __builtin_amdgcn_exp2f(us * C2);

    // ---- D: score partial over this half's 64 k; E from LDS, U/v2 via readlane ----
    const float* Erow = &sm.E[t * EST + 64 * half];
    float a0 = 0.0f, a1 = 0.0f;
    #pragma unroll
    for (int q = 0; q < 16; ++q) {
      float4 ev = *(const float4*)(Erow + 4 * q);
      float s0 = rdlane(Ur, 4 * q + 0);
      float s1 = rdlane(Ur, 4 * q + 1);
      float s2 = rdlane(Ur, 4 * q + 2);
      float s3 = rdlane(Ur, 4 * q + 3);
      a0 += rdlane(v2r, 4 * q + 0) * __builtin_amdgcn_rcpf(1.0f + ev.x * s0);
      a1 += rdlane(v2r, 4 * q + 1) * __builtin_amdgcn_rcpf(1.0f + ev.y * s1);
      a0 += rdlane(v2r, 4 * q + 2) * __builtin_amdgcn_rcpf(1.0f + ev.z * s2);
      a1 += rdlane(v2r, 4 * q + 3) * __builtin_amdgcn_rcpf(1.0f + ev.w * s3);
    }
    float myacc = a0 + a1;
    sm.scp[w][lane] = myacc;
    __syncthreads();               // (delta) partner partial visible

    float score = svr + myacc + sm.scp[w ^ 1][lane];

    // softmax numerator with fixed shift (|score| <= ~10.5, B=12: no overflow,
    // no underflow; softmax is shift-invariant so p/sum is exact)
    float p = __builtin_amdgcn_exp2f((score - 12.0f) * L2E);

    // wave argmax (first-max tie-break) + wave sum
    float bs = score; int bt = t;
    float ws = p;
    #pragma unroll
    for (int o = 1; o < 64; o <<= 1) {
      float s2v = __shfl_xor(bs, o);
      int   t2v = __shfl_xor(bt, o);
      if (s2v > bs || (s2v == bs && t2v < bt)) { bs = s2v; bt = t2v; }
      ws += __shfl_xor(ws, o);
    }
    if (half == 0 && lane == 0) {
      sm.amax_s[tq] = bs; sm.amax_t[tq] = bt; sm.ssum[tq] = ws;
    }
    __syncthreads();               // (eps) block partials visible

    float fbs = sm.amax_s[0]; int fbt = sm.amax_t[0];
    #pragma unroll
    for (int q = 1; q < 4; ++q) {
      float s2v = sm.amax_s[q]; int t2v = sm.amax_t[q];
      if (s2v > fbs || (s2v == fbs && t2v < fbt)) { fbs = s2v; fbt = t2v; }
    }
    float sumtot = (sm.ssum[0] + sm.ssum[1]) + (sm.ssum[2] + sm.ssum[3]);
    ptr0 = sm.xloc[fbt * 2 + 0];
    ptr1 = sm.xloc[fbt * 2 + 1];
    if (half == 0) outb[(size_t)step * TT + t] = p * __builtin_amdgcn_rcpf(sumtot);
  }
}

extern "C" void kernel_launch(void* const* d_in, const int* in_sizes, int n_in,
                              void* d_out, int out_size, void* d_ws, size_t ws_size,
                              hipStream_t stream) {
  (void)in_sizes; (void)n_in; (void)d_ws; (void)ws_size; (void)out_size;
  const float* x    = (const float*)d_in[0];
  const float* enc  = (const float*)d_in[1];
  const float* h0   = (const float*)d_in[2];
  const float* c0   = (const float*)d_in[3];
  const float* W1   = (const float*)d_in[4];
  const float* W2   = (const float*)d_in[5];
  const float* V    = (const float*)d_in[6];
  const float* Wk   = (const float*)d_in[7];
  const float* Wr   = (const float*)d_in[8];
  const float* bias = (const float*)d_in[9];
  float* out = (float*)d_out;

  decoder_kernel<<<64, 512, 0, stream>>>(x, enc, h0, c0, W1, W2, V, Wk, Wr, bias, out);
}